// Round 1
// baseline (37.214 us; speedup 1.0000x reference)
//
#include <hip/hip_runtime.h>
#include <hip/hip_bf16.h>

typedef unsigned int   u32;
typedef unsigned short u16;

#define NN   8192
#define DD   128
#define CCH  16            // column chunks (grid.x)
#define CHUNK (NN / CCH)   // 512 columns per block
#define JT   64            // j-tile staged in LDS
#define LDST 136           // LDS row stride in ushort (128 + 8 pad -> 272B, kills bank conflicts)

#define LOG2E 1.4426950408889634f
#define LN2F  0.6931471805599453f
#define BIAS  32.0f

typedef __bf16 bf16x8 __attribute__((ext_vector_type(8)));
typedef float  f32x4  __attribute__((ext_vector_type(4)));

__device__ __forceinline__ u16 f2bf(float x) {
    u32 u = __float_as_uint(x);
    u += 0x7fffu + ((u >> 16) & 1u);   // round-to-nearest-even
    return (u16)(u >> 16);
}

// One wave per row: convert z1,z2 to bf16, compute -sq2*log2e - BIAS and fp32 diagonal.
__global__ __launch_bounds__(256) void prep_kernel(
    const float* __restrict__ z1, const float* __restrict__ z2,
    u32* __restrict__ b1, u32* __restrict__ b2,
    float* __restrict__ negsq2b, float* __restrict__ diag)
{
    int row  = blockIdx.x * 4 + (threadIdx.x >> 6);
    int lane = threadIdx.x & 63;
    float2 a = reinterpret_cast<const float2*>(z1)[row * 64 + lane];
    float2 b = reinterpret_cast<const float2*>(z2)[row * 64 + lane];
    b1[row * 64 + lane] = (u32)f2bf(a.x) | ((u32)f2bf(a.y) << 16);
    b2[row * 64 + lane] = (u32)f2bf(b.x) | ((u32)f2bf(b.y) << 16);
    float dot = a.x * b.x + a.y * b.y;
    float sq  = b.x * b.x + b.y * b.y;
    #pragma unroll
    for (int o = 32; o > 0; o >>= 1) {
        dot += __shfl_xor(dot, o);
        sq  += __shfl_xor(sq, o);
    }
    if (lane == 0) {
        negsq2b[row] = -sq * LOG2E - BIAS;
        diag[row]    = 2.0f * dot - sq;
    }
}

// Main: each block = 4 waves x 32 rows (128 rows), sweeps CHUNK columns.
// Swapped MFMA: D[j][i] = z2_j . z1_i ; lane holds col i = lane&15, rows j = (lane>>4)*4+reg.
// Fixed-bias exp sum: sum_j 2^( dot*2log2e - sq2*log2e - BIAS ), no online max needed.
__global__ __launch_bounds__(256, 4) void score_kernel(
    const u16* __restrict__ b1, const u16* __restrict__ b2,
    const float* __restrict__ negsq2b, float* __restrict__ partS)
{
    __shared__ alignas(16) u16 tile[JT * LDST];
    const int tid  = threadIdx.x;
    const int lane = tid & 63;
    const int wid  = tid >> 6;
    const int llo  = lane & 15, lhi = lane >> 4;
    const int chunk = blockIdx.x;
    const int i0    = blockIdx.y * 128 + wid * 32;   // wave's first z1 row
    const int j0    = chunk * CHUNK;

    // z1 fragments, register-resident for the whole column sweep.
    bf16x8 zf0[4], zf1[4];
    #pragma unroll
    for (int kk = 0; kk < 4; ++kk) {
        zf0[kk] = *reinterpret_cast<const bf16x8*>(b1 + (size_t)(i0 + llo)      * DD + kk * 32 + lhi * 8);
        zf1[kk] = *reinterpret_cast<const bf16x8*>(b1 + (size_t)(i0 + 16 + llo) * DD + kk * 32 + lhi * 8);
    }

    float sum0 = 0.f, sum1 = 0.f;
    const float C2 = 2.0f * LOG2E;

    for (int jt = 0; jt < CHUNK; jt += JT) {
        __syncthreads();
        // stage 64 z2 rows into LDS (padded stride), fully coalesced 16B loads
        #pragma unroll
        for (int u = 0; u < 4; ++u) {
            int idx = u * 256 + tid;
            int row = idx >> 4, colb = idx & 15;
            *reinterpret_cast<uint4*>(&tile[row * LDST + colb * 8]) =
                *reinterpret_cast<const uint4*>(b2 + (size_t)(j0 + jt + row) * DD + colb * 8);
        }
        __syncthreads();
        #pragma unroll
        for (int jj = 0; jj < 4; ++jj) {
            bf16x8 av[4];
            const int ar = jj * 16 + llo;
            #pragma unroll
            for (int kk = 0; kk < 4; ++kk)
                av[kk] = *reinterpret_cast<const bf16x8*>(&tile[ar * LDST + kk * 32 + lhi * 8]);
            f32x4 acc0 = {0.f, 0.f, 0.f, 0.f};
            f32x4 acc1 = {0.f, 0.f, 0.f, 0.f};
            #pragma unroll
            for (int kk = 0; kk < 4; ++kk) {
                acc0 = __builtin_amdgcn_mfma_f32_16x16x32_bf16(av[kk], zf0[kk], acc0, 0, 0, 0);
                acc1 = __builtin_amdgcn_mfma_f32_16x16x32_bf16(av[kk], zf1[kk], acc1, 0, 0, 0);
            }
            const float4 nsq = *reinterpret_cast<const float4*>(negsq2b + j0 + jt + jj * 16 + lhi * 4);
            const float nq[4] = {nsq.x, nsq.y, nsq.z, nsq.w};
            #pragma unroll
            for (int r = 0; r < 4; ++r) {
                sum0 += __builtin_amdgcn_exp2f(fmaf(acc0[r], C2, nq[r]));
                sum1 += __builtin_amdgcn_exp2f(fmaf(acc1[r], C2, nq[r]));
            }
        }
    }
    // each output row's partial sum lives in 4 lanes {l, l^16, l^32, l^48}
    sum0 += __shfl_xor(sum0, 16); sum0 += __shfl_xor(sum0, 32);
    sum1 += __shfl_xor(sum1, 16); sum1 += __shfl_xor(sum1, 32);
    if (lhi == 0) {
        partS[(size_t)chunk * NN + i0 + llo]      = sum0;
        partS[(size_t)chunk * NN + i0 + 16 + llo] = sum1;
    }
}

// Combine the 16 column-chunk partials per row, form lse - diag, block-reduce.
__global__ __launch_bounds__(256) void finalize1_kernel(
    const float* __restrict__ partS, const float* __restrict__ diag,
    float* __restrict__ blocksum)
{
    __shared__ float red[4];
    int r = blockIdx.x * 256 + threadIdx.x;
    float s = 0.f;
    #pragma unroll
    for (int c = 0; c < CCH; ++c) s += partS[(size_t)c * NN + r];
    float lse = (BIAS + __builtin_amdgcn_logf(s)) * LN2F;   // v_log_f32 = log2
    float acc = lse - diag[r];
    #pragma unroll
    for (int o = 32; o > 0; o >>= 1) acc += __shfl_xor(acc, o);
    int lane = threadIdx.x & 63, wid = threadIdx.x >> 6;
    if (lane == 0) red[wid] = acc;
    __syncthreads();
    if (threadIdx.x == 0)
        blocksum[blockIdx.x] = red[0] + red[1] + red[2] + red[3];
}

__global__ void finalize2_kernel(const float* __restrict__ blocksum, float* __restrict__ out)
{
    int lane = threadIdx.x;
    float v = (lane < 32) ? blocksum[lane] : 0.f;
    #pragma unroll
    for (int o = 32; o > 0; o >>= 1) v += __shfl_xor(v, o);
    if (lane == 0) out[0] = v * (1.0f / (float)NN);
}

extern "C" void kernel_launch(void* const* d_in, const int* in_sizes, int n_in,
                              void* d_out, int out_size, void* d_ws, size_t ws_size,
                              hipStream_t stream)
{
    const float* z1 = (const float*)d_in[0];
    const float* z2 = (const float*)d_in[1];
    char* ws = (char*)d_ws;

    const size_t bf_bytes = (size_t)NN * DD * 2;   // 2 MB each
    u32*   b1       = (u32*)ws;
    u32*   b2       = (u32*)(ws + bf_bytes);
    float* negsq2b  = (float*)(ws + 2 * bf_bytes);
    float* diag     = (float*)(ws + 2 * bf_bytes + (size_t)NN * 4);
    float* partS    = (float*)(ws + 2 * bf_bytes + (size_t)NN * 8);
    float* blocksum = (float*)(ws + 2 * bf_bytes + (size_t)NN * 8 + (size_t)CCH * NN * 4);
    float* out      = (float*)d_out;

    prep_kernel<<<NN / 4, 256, 0, stream>>>(z1, z2, b1, b2, negsq2b, diag);
    score_kernel<<<dim3(CCH, NN / 128), 256, 0, stream>>>((const u16*)b1, (const u16*)b2, negsq2b, partS);
    finalize1_kernel<<<NN / 256, 256, 0, stream>>>(partS, diag, blocksum);
    finalize2_kernel<<<1, 64, 0, stream>>>(blocksum, out);
}

// Round 2
// 35.964 us; speedup vs baseline: 1.0348x; 1.0348x over previous
//
#include <hip/hip_runtime.h>
#include <hip/hip_bf16.h>

typedef unsigned int   u32;
typedef unsigned short u16;

#define NN   8192
#define DD   128
#define CCH  16            // column chunks (grid.x)
#define CHUNK (NN / CCH)   // 512 columns per block
#define JT   64            // j-tile staged in LDS
#define NT   (CHUNK / JT)  // 8 tiles per block

#define LOG2E 1.4426950408889634f
#define LN2F  0.6931471805599453f
#define BIAS  32.0f

typedef __bf16 bf16x8 __attribute__((ext_vector_type(8)));
typedef float  f32x16 __attribute__((ext_vector_type(16)));
typedef float  f32x2  __attribute__((ext_vector_type(2)));

__device__ __forceinline__ u16 f2bf(float x) {
    u32 u = __float_as_uint(x);
    u += 0x7fffu + ((u >> 16) & 1u);   // round-to-nearest-even
    return (u16)(u >> 16);
}

// One wave per row: convert z1,z2 to bf16, compute -sq2*log2e - BIAS and fp32 diagonal.
__global__ __launch_bounds__(256) void prep_kernel(
    const float* __restrict__ z1, const float* __restrict__ z2,
    u32* __restrict__ b1, u32* __restrict__ b2,
    float* __restrict__ negsq2b, float* __restrict__ diag)
{
    int row  = blockIdx.x * 4 + (threadIdx.x >> 6);
    int lane = threadIdx.x & 63;
    float2 a = reinterpret_cast<const float2*>(z1)[row * 64 + lane];
    float2 b = reinterpret_cast<const float2*>(z2)[row * 64 + lane];
    b1[row * 64 + lane] = (u32)f2bf(a.x) | ((u32)f2bf(a.y) << 16);
    b2[row * 64 + lane] = (u32)f2bf(b.x) | ((u32)f2bf(b.y) << 16);
    float dot = a.x * b.x + a.y * b.y;
    float sq  = b.x * b.x + b.y * b.y;
    #pragma unroll
    for (int o = 32; o > 0; o >>= 1) {
        dot += __shfl_xor(dot, o);
        sq  += __shfl_xor(sq, o);
    }
    if (lane == 0) {
        negsq2b[row] = -sq * LOG2E - BIAS;
        diag[row]    = 2.0f * dot - sq;
    }
}

// Main: 4 waves x 64 i-rows = 256 rows/block, sweeping CHUNK j-columns.
// mfma_f32_32x32x16_bf16, swapped operands: D[j][i] = z2_j . z1_i.
//   A (z2 from LDS):  m = lane&31, k = (lane>>5)*8 + e  (per 16-k slice kk)
//   B (z1 in regs):   n = lane&31, same k map
//   C/D:              col i = lane&31, row j = (reg&3) + 8*(reg>>2) + 4*(lane>>5)
// LDS: linear [64][128] u16 rows, 16B slots XOR-swizzled by (row&15); filled with
// global_load_lds width=16 from a pre-swizzled per-lane GLOBAL source (rule #21).
// Single barrier per tile, double-buffered: issue tile t+1 right after the barrier.
__global__ __launch_bounds__(256, 2) void score_kernel(
    const u16* __restrict__ b1, const u16* __restrict__ b2,
    const float* __restrict__ negsq2b, float* __restrict__ partS)
{
    __shared__ alignas(16) u16 tile[2][JT * DD];   // 2 x 16 KB
    const int tid  = threadIdx.x;
    const int lane = tid & 63;
    const int wid  = tid >> 6;
    const int r    = lane & 31, hi = lane >> 5;
    const int chunk = blockIdx.x;
    const int j0    = chunk * CHUNK;
    const int i0w   = blockIdx.y * 256 + wid * 64;

    // z1 fragments (B operand), register-resident: 2 spans x 8 k-slices
    bf16x8 zf0[8], zf1[8];
    #pragma unroll
    for (int kk = 0; kk < 8; ++kk) {
        zf0[kk] = *reinterpret_cast<const bf16x8*>(b1 + (size_t)(i0w + r)      * DD + kk * 16 + hi * 8);
        zf1[kk] = *reinterpret_cast<const bf16x8*>(b1 + (size_t)(i0w + 32 + r) * DD + kk * 16 + hi * 8);
    }

    const int sl   = lane & 15;    // staging slot
    const int rrow = lane >> 4;    // staging row-within-4

    auto stage = [&](int t, int buf) {
        #pragma unroll
        for (int u = 0; u < 4; ++u) {
            int row   = wid * 16 + u * 4 + rrow;           // local row 0..63
            int gslot = sl ^ (row & 15);                   // inverse-swizzled source
            const u16* src = b2 + (size_t)(j0 + t * JT + row) * DD + gslot * 8;
            u16* dst = &tile[buf][(wid * 16 + u * 4) * DD]; // wave-uniform; +lane*16B implicit
            __builtin_amdgcn_global_load_lds(
                (const __attribute__((address_space(1))) void*)src,
                (__attribute__((address_space(3))) void*)dst, 16, 0, 0);
        }
    };

    float s0 = 0.f, s1 = 0.f, s2 = 0.f, s3 = 0.f;
    const f32x2 C2v = {2.0f * LOG2E, 2.0f * LOG2E};
    const int sw = r & 15;   // read-side swizzle key (row&15 == r&15, jj*32 ≡ 0 mod 16)

    int cur = 0;
    stage(0, 0);
    for (int t = 0; t < NT; ++t) {
        __syncthreads();                   // drains vmcnt(0): buf[cur] ready, buf[cur^1] free
        if (t + 1 < NT) stage(t + 1, cur ^ 1);
        const u16* tp = tile[cur];
        #pragma unroll
        for (int jj = 0; jj < 2; ++jj) {
            const float* nqb = negsq2b + j0 + t * JT + jj * 32 + 4 * hi;
            float4 nq0 = *reinterpret_cast<const float4*>(nqb);
            float4 nq1 = *reinterpret_cast<const float4*>(nqb + 8);
            float4 nq2 = *reinterpret_cast<const float4*>(nqb + 16);
            float4 nq3 = *reinterpret_cast<const float4*>(nqb + 24);
            bf16x8 av[8];
            #pragma unroll
            for (int kk = 0; kk < 8; ++kk) {
                int off = (jj * 32 + r) * DD + (((2 * kk + hi) ^ sw) << 3);
                av[kk] = *reinterpret_cast<const bf16x8*>(tp + off);
            }
            f32x16 acc0 = {0.f}; f32x16 acc1 = {0.f};
            #pragma unroll
            for (int kk = 0; kk < 8; ++kk) {
                acc0 = __builtin_amdgcn_mfma_f32_32x32x16_bf16(av[kk], zf0[kk], acc0, 0, 0, 0);
                acc1 = __builtin_amdgcn_mfma_f32_32x32x16_bf16(av[kk], zf1[kk], acc1, 0, 0, 0);
            }
            const float nqa[16] = {nq0.x, nq0.y, nq0.z, nq0.w,
                                   nq1.x, nq1.y, nq1.z, nq1.w,
                                   nq2.x, nq2.y, nq2.z, nq2.w,
                                   nq3.x, nq3.y, nq3.z, nq3.w};
            #pragma unroll
            for (int q = 0; q < 8; ++q) {
                f32x2 n2 = {nqa[2 * q], nqa[2 * q + 1]};
                f32x2 a0 = {acc0[2 * q], acc0[2 * q + 1]};
                f32x2 t0 = a0 * C2v + n2;
                s0 += __builtin_amdgcn_exp2f(t0.x);
                s1 += __builtin_amdgcn_exp2f(t0.y);
                f32x2 a1 = {acc1[2 * q], acc1[2 * q + 1]};
                f32x2 t1 = a1 * C2v + n2;
                s2 += __builtin_amdgcn_exp2f(t1.x);
                s3 += __builtin_amdgcn_exp2f(t1.y);
            }
        }
        cur ^= 1;
    }

    float sum0 = s0 + s1, sum1 = s2 + s3;
    sum0 += __shfl_xor(sum0, 32);          // combine hi=0/1 j-halves per i
    sum1 += __shfl_xor(sum1, 32);
    if (hi == 0) {
        partS[(size_t)chunk * NN + i0w + r]      = sum0;
        partS[(size_t)chunk * NN + i0w + 32 + r] = sum1;
    }
}

// Combine the 16 column-chunk partials per row, form lse - diag, block-reduce.
__global__ __launch_bounds__(256) void finalize1_kernel(
    const float* __restrict__ partS, const float* __restrict__ diag,
    float* __restrict__ blocksum)
{
    __shared__ float red[4];
    int r = blockIdx.x * 256 + threadIdx.x;
    float s = 0.f;
    #pragma unroll
    for (int c = 0; c < CCH; ++c) s += partS[(size_t)c * NN + r];
    float lse = (BIAS + __builtin_amdgcn_logf(s)) * LN2F;   // v_log_f32 = log2
    float acc = lse - diag[r];
    #pragma unroll
    for (int o = 32; o > 0; o >>= 1) acc += __shfl_xor(acc, o);
    int lane = threadIdx.x & 63, wid = threadIdx.x >> 6;
    if (lane == 0) red[wid] = acc;
    __syncthreads();
    if (threadIdx.x == 0)
        blocksum[blockIdx.x] = red[0] + red[1] + red[2] + red[3];
}

__global__ void finalize2_kernel(const float* __restrict__ blocksum, float* __restrict__ out)
{
    int lane = threadIdx.x;
    float v = (lane < 32) ? blocksum[lane] : 0.f;
    #pragma unroll
    for (int o = 32; o > 0; o >>= 1) v += __shfl_xor(v, o);
    if (lane == 0) out[0] = v * (1.0f / (float)NN);
}

extern "C" void kernel_launch(void* const* d_in, const int* in_sizes, int n_in,
                              void* d_out, int out_size, void* d_ws, size_t ws_size,
                              hipStream_t stream)
{
    const float* z1 = (const float*)d_in[0];
    const float* z2 = (const float*)d_in[1];
    char* ws = (char*)d_ws;

    const size_t bf_bytes = (size_t)NN * DD * 2;   // 2 MB each
    u32*   b1       = (u32*)ws;
    u32*   b2       = (u32*)(ws + bf_bytes);
    float* negsq2b  = (float*)(ws + 2 * bf_bytes);
    float* diag     = (float*)(ws + 2 * bf_bytes + (size_t)NN * 4);
    float* partS    = (float*)(ws + 2 * bf_bytes + (size_t)NN * 8);
    float* blocksum = (float*)(ws + 2 * bf_bytes + (size_t)NN * 8 + (size_t)CCH * NN * 4);
    float* out      = (float*)d_out;

    prep_kernel<<<NN / 4, 256, 0, stream>>>(z1, z2, b1, b2, negsq2b, diag);
    score_kernel<<<dim3(CCH, NN / 256), 256, 0, stream>>>((const u16*)b1, (const u16*)b2, negsq2b, partS);
    finalize1_kernel<<<NN / 256, 256, 0, stream>>>(partS, diag, blocksum);
    finalize2_kernel<<<1, 64, 0, stream>>>(blocksum, out);
}